// Round 19
// baseline (161.493 us; speedup 1.0000x reference)
//
#include <hip/hip_runtime.h>
#include <stdint.h>

#define B_    4
#define C_    256
#define W_    4096
#define DQK_  32
#define NT64_ 64      // 64-wide n tiles per batch
#define TSZ_  16384   // shorts per x0f tile (8 wb x 4 frag x 64 lane x 8)

typedef short bf16x8 __attribute__((ext_vector_type(8)));
typedef float f32x4  __attribute__((ext_vector_type(4)));

__device__ __forceinline__ float fexp2f(float x){
#if __has_builtin(__builtin_amdgcn_exp2f)
  return __builtin_amdgcn_exp2f(x);
#else
  return exp2f(x);
#endif
}
__device__ __forceinline__ float frcpf(float x){
#if __has_builtin(__builtin_amdgcn_rcpf)
  return __builtin_amdgcn_rcpf(x);
#else
  return 1.0f / x;
#endif
}
// single-instruction packed f32->bf16 (RTNE)
__device__ __forceinline__ uint32_t cvtpk(float a, float b){
  uint32_t r;
  asm("v_cvt_pk_bf16_f32 %0, %1, %2" : "=v"(r) : "v"(a), "v"(b));
  return r;
}
__device__ __forceinline__ unsigned short bf16c(float f){
  return (unsigned short)cvtpk(f, f);
}

// ---------------------------------------------------------------------------
// K1: UNCHANGED from R15 (wave-uniform weight c-slices -> scalar broadcasts).
// ---------------------------------------------------------------------------
__global__ __launch_bounds__(512) void sa_prep(
    const float* __restrict__ x0, const float* __restrict__ x1,
    const float* __restrict__ wq, const float* __restrict__ bq,
    const float* __restrict__ wk, const float* __restrict__ bk,
    unsigned short* __restrict__ qf, unsigned short* __restrict__ kT,
    unsigned short* __restrict__ x0f)
{
  const int b    = blockIdx.y;
  const int nt   = blockIdx.x;                 // 64-n tile index
  const int tid  = threadIdx.x;
  const int lane = tid & 63;
  const int cq   = __builtin_amdgcn_readfirstlane(tid >> 6);   // 0..7, uniform
  const int n    = nt * 64 + lane;
  const int lr   = lane & 15, lg = lane >> 4;
  const size_t bw = (size_t)b * ((size_t)C_ * W_) + n;

  __shared__ union {
    unsigned short xs[256 * 68];   // bf16 stage [c][n-local], pitch 68
    float red[8][64][33];          // cross-wave reduce
  } sm;

  float accq[DQK_], acck[DQK_];
  #pragma unroll
  for (int d = 0; d < DQK_; ++d){ accq[d] = 0.f; acck[d] = 0.f; }

  const int c0 = cq * 32;
  for (int i = 0; i < 32; ++i){
    const int c = c0 + i;                      // wave-uniform
    const size_t off = bw + (size_t)c * W_;
    const float v0 = x0[off];
    const float v1 = x1[off];
    sm.xs[c * 68 + lane] = bf16c(v0);
    #pragma unroll
    for (int d = 0; d < DQK_; ++d){
      accq[d] = fmaf(wq[d * C_ + c], v0, accq[d]);   // scalar loads (uniform)
      acck[d] = fmaf(wk[d * C_ + c], v1, acck[d]);
    }
  }

  // ---- flush x0f (intra-wave dependency only) ----
  {
    unsigned short* xt = x0f + (size_t)(b * NT64_ + nt) * TSZ_;
    #pragma unroll
    for (int ct = 0; ct < 2; ++ct)
      #pragma unroll
      for (int ks = 0; ks < 2; ++ks){
        uint4 v = *(const uint4*)&sm.xs[(c0 + ct * 16 + lr) * 68 + ks * 32 + lg * 8];
        *(uint4*)(xt + ((size_t)((cq * 2 + ct) * 2 + ks) * 64 + lane) * 8) = v;
      }
  }
  __syncthreads();   // xs reads done -> red may overwrite

  // ---- q reduce + fragment-layout pack ----
  #pragma unroll
  for (int d = 0; d < DQK_; ++d) sm.red[cq][lane][d] = accq[d];
  __syncthreads();
  {
    const int nl = tid & 63, dg = tid >> 6;
    const int d0 = dg * 4;
    float s[4];
    #pragma unroll
    for (int j = 0; j < 4; ++j){
      float t = bq[d0 + j];
      #pragma unroll
      for (int g = 0; g < 8; ++g) t += sm.red[g][nl][d0 + j];
      s[j] = t;
    }
    uint2 pk; pk.x = cvtpk(s[0], s[1]); pk.y = cvtpk(s[2], s[3]);
    const int ng = nt * 64 + nl;
    const size_t addr = (((size_t)b * 256 + (ng >> 4)) * 64
                         + (ng & 15) + ((dg >> 1) << 4)) * 8 + (dg & 1) * 4;
    *(uint2*)(qf + addr) = pk;
  }
  __syncthreads();

  // ---- k reduce + row-major pack (scaled) ----
  #pragma unroll
  for (int d = 0; d < DQK_; ++d) sm.red[cq][lane][d] = acck[d];
  __syncthreads();
  {
    const float SCL = 0.0625f * 1.44269504088896340736f; // 1/sqrt(256)*log2(e)
    const int nl = tid & 63, dg = tid >> 6;
    const int d0 = dg * 4;
    float s[4];
    #pragma unroll
    for (int j = 0; j < 4; ++j){
      float t = bk[d0 + j];
      #pragma unroll
      for (int g = 0; g < 8; ++g) t += sm.red[g][nl][d0 + j];
      s[j] = t * SCL;
    }
    uint2 pk; pk.x = cvtpk(s[0], s[1]); pk.y = cvtpk(s[2], s[3]);
    *(uint2*)(kT + ((size_t)b * W_ + nt * 64 + nl) * DQK_ + d0) = pk;
  }
}

// ---------------------------------------------------------------------------
// K2 (R19): BARRIER-FREE fused kernel. Block = 4 waves (256 thr), m-tile 16.
// Wave nq owns n-window [ep*128 + nq*32, +32) per epoch. Per epoch:
//   2 energy MFMA -> P[n][m] lane-local (transposed) -> exp2*invS ->
//   att f32x4 stores DIRECT from regs -> in-register P transpose to B-frag
//   via 8 ds_bpermute + 4 selects -> 16 PV MFMA vs register x0f fragments
//   (double-buffered one epoch ahead, ~240 VGPR, 2 waves/SIMD).
// NO barriers / NO LDS tile / NO vmcnt drains in the loops -> waves run
// independent chains; VMEM, LDS-pipe, MFMA, VALU overlap via TLP.
// Sync: 1 barrier for invS + 4 short reduce rounds at epilogue.
// grid 1024 (XCD-paired per batch).
// ---------------------------------------------------------------------------
__global__ __launch_bounds__(256, 2) void sa_fused(
    const unsigned short* __restrict__ qf, const unsigned short* __restrict__ kT,
    const unsigned short* __restrict__ x0f, const float* __restrict__ x1,
    const float* __restrict__ gamma,
    float* __restrict__ out, float* __restrict__ att)
{
  const int lb = blockIdx.x;
  const int b    = (lb & 7) >> 1;                    // batch -> XCD pair
  const int mblk = ((lb >> 3) << 1) | (lb & 1);      // 0..255
  const int m0 = mblk * 16;
  const int lane = threadIdx.x & 63;
  const int nq  = threadIdx.x >> 6;                  // 0..3 (wave id = n-slice)
  const int lr = lane & 15, lg = lane >> 4;

  __shared__ float ssum[4][16];
  __shared__ __align__(16) float red[4][4][64][4];   // 16KB epilogue reduce

  const f32x4 z4 = {0.f, 0.f, 0.f, 0.f};
  const bf16x8 kf = *(const bf16x8*)(kT + ((size_t)b * W_ + m0 + lr) * DQK_ + lg * 8);
  // q fragment stream: tile t = 8*ep + 2*nq (+1); addr = base + t*512 shorts
  const unsigned short* qf0 = qf + ((size_t)b * 256 * 64 + lane) * 8 + (size_t)(2 * nq) * 512;
  // x0f fragments: epoch ep -> 64-tile nt = 2*ep + (nq>>1), half ks = nq&1
  const unsigned short* afb = x0f + ((size_t)b * NT64_ + (nq >> 1)) * TSZ_
                              + (size_t)(nq & 1) * 512 + (size_t)lane * 8;

  // bpermute source byte-indices (within-wave P transpose)
  const int sA = (lr + 32 * (lg & 1)) * 4;   // u32 j=0,1 source lane
  const int sB = sA + 64;                    // u32 j=2,3 source lane (+16)

  // ---- pass 1: denominators (energy-only, barrier-free) ----
  float ps = 0.f;
  {
    const unsigned short* qp = qf0;
    bf16x8 qv0 = *(const bf16x8*)qp;
    bf16x8 qv1 = *(const bf16x8*)(qp + 512);
    for (int ep = 0; ep < 32; ++ep){
      f32x4 e0 = __builtin_amdgcn_mfma_f32_16x16x32_bf16(qv0, kf, z4, 0, 0, 0);
      f32x4 e1 = __builtin_amdgcn_mfma_f32_16x16x32_bf16(qv1, kf, z4, 0, 0, 0);
      if (ep != 31){
        qp += 4096;                      // 8 tiles * 512 shorts
        qv0 = *(const bf16x8*)qp;
        qv1 = *(const bf16x8*)(qp + 512);
      }
      ps += (fexp2f(e0[0]) + fexp2f(e0[1])) + (fexp2f(e0[2]) + fexp2f(e0[3]))
          + (fexp2f(e1[0]) + fexp2f(e1[1])) + (fexp2f(e1[2]) + fexp2f(e1[3]));
    }
  }
  // sum over n for fixed m=lr: reduce across lg groups
  ps += __shfl_xor(ps, 16);
  ps += __shfl_xor(ps, 32);
  if (lane < 16) ssum[nq][lane] = ps;
  __syncthreads();
  const float is = frcpf(ssum[0][lr] + ssum[1][lr] + ssum[2][lr] + ssum[3][lr]);

  // ---- pass 2: barrier-free main loop ----
  f32x4 acc[16];
  #pragma unroll
  for (int i = 0; i < 16; ++i) acc[i] = z4;

  bf16x8 afA[16], afB[16];
  const unsigned short* afp = afb;
  #pragma unroll
  for (int i = 0; i < 16; ++i) afA[i] = *(const bf16x8*)(afp + i * 1024);

  const unsigned short* qp = qf0;
  bf16x8 qv0 = *(const bf16x8*)qp;
  bf16x8 qv1 = *(const bf16x8*)(qp + 512);
  float* attw = att + ((size_t)b * W_ + m0 + lr) * W_ + nq * 32 + lg * 4;

  #define EPOCH_BODY(AFU, AFL, DO_LOAD)                                          \
  {                                                                              \
    f32x4 e0 = __builtin_amdgcn_mfma_f32_16x16x32_bf16(qv0, kf, z4, 0, 0, 0);    \
    f32x4 e1 = __builtin_amdgcn_mfma_f32_16x16x32_bf16(qv1, kf, z4, 0, 0, 0);    \
    if (DO_LOAD){                                                                \
      qp += 4096;                                                                \
      qv0 = *(const bf16x8*)qp;                                                  \
      qv1 = *(const bf16x8*)(qp + 512);                                          \
    }                                                                            \
    f32x4 p0, p1;                                                                \
    _Pragma("unroll")                                                            \
    for (int r = 0; r < 4; ++r){                                                 \
      p0[r] = fexp2f(e0[r]) * is;                                                \
      p1[r] = fexp2f(e1[r]) * is;                                                \
    }                                                                            \
    *(f32x4*)attw = p0;                                                          \
    *(f32x4*)(attw + 16) = p1;                                                   \
    attw += 128;                                                                 \
    if (DO_LOAD){                                                                \
      afp += 2 * TSZ_;                                                           \
      _Pragma("unroll")                                                          \
      for (int i = 0; i < 16; ++i) AFL[i] = *(const bf16x8*)(afp + i * 1024);    \
    }                                                                            \
    const uint32_t c0 = cvtpk(p0[0], p0[1]), c1 = cvtpk(p0[2], p0[3]);           \
    const uint32_t c2 = cvtpk(p1[0], p1[1]), c3 = cvtpk(p1[2], p1[3]);           \
    const uint32_t a0 = (uint32_t)__builtin_amdgcn_ds_bpermute(sA, (int)c0);     \
    const uint32_t a1 = (uint32_t)__builtin_amdgcn_ds_bpermute(sA, (int)c1);     \
    const uint32_t a2 = (uint32_t)__builtin_amdgcn_ds_bpermute(sB, (int)c0);     \
    const uint32_t a3 = (uint32_t)__builtin_amdgcn_ds_bpermute(sB, (int)c1);     \
    const uint32_t b0 = (uint32_t)__builtin_amdgcn_ds_bpermute(sA, (int)c2);     \
    const uint32_t b1 = (uint32_t)__builtin_amdgcn_ds_bpermute(sA, (int)c3);     \
    const uint32_t b2 = (uint32_t)__builtin_amdgcn_ds_bpermute(sB, (int)c2);     \
    const uint32_t b3 = (uint32_t)__builtin_amdgcn_ds_bpermute(sB, (int)c3);     \
    union { uint32_t u[4]; bf16x8 v; } pfu;                                      \
    const bool hi = (lg & 2) != 0;                                               \
    pfu.u[0] = hi ? b0 : a0;                                                     \
    pfu.u[1] = hi ? b1 : a1;                                                     \
    pfu.u[2] = hi ? b2 : a2;                                                     \
    pfu.u[3] = hi ? b3 : a3;                                                     \
    const bf16x8 pf = pfu.v;                                                     \
    _Pragma("unroll")                                                            \
    for (int i = 0; i < 16; ++i)                                                 \
      acc[i] = __builtin_amdgcn_mfma_f32_16x16x32_bf16(AFU[i], pf, acc[i], 0, 0, 0); \
  }

  for (int ep2 = 0; ep2 < 16; ++ep2){
    EPOCH_BODY(afA, afB, 1);                 // even epoch: use A, load B
    EPOCH_BODY(afB, afA, (ep2 != 15));       // odd epoch: use B, load A
  }
  #undef EPOCH_BODY

  // ---- epilogue: cross-wave (nq) reduce + out = gamma*acc + x1 ----
  const float g = gamma[0];
  const float* x1b = x1 + (size_t)b * C_ * W_;
  float* outb = out + (size_t)b * C_ * W_;
  #pragma unroll
  for (int grp = 0; grp < 4; ++grp){
    __syncthreads();
    #pragma unroll
    for (int j = 0; j < 4; ++j)
      *(f32x4*)&red[nq][j][lane][0] = acc[grp * 4 + j];
    __syncthreads();
    // wave nq reduces c-tile ct = grp*4 + nq
    f32x4 s = *(const f32x4*)&red[0][nq][lane][0];
    #pragma unroll
    for (int w = 1; w < 4; ++w) s += *(const f32x4*)&red[w][nq][lane][0];
    const int ct = grp * 4 + nq;
    #pragma unroll
    for (int r = 0; r < 4; ++r){
      const int c = ct * 16 + lg * 4 + r;
      const size_t idx = (size_t)c * W_ + m0 + lr;
      outb[idx] = fmaf(g, s[r], x1b[idx]);
    }
  }
}

extern "C" void kernel_launch(void* const* d_in, const int* in_sizes, int n_in,
                              void* d_out, int out_size, void* d_ws, size_t ws_size,
                              hipStream_t stream)
{
  (void)in_sizes; (void)n_in; (void)out_size; (void)ws_size;
  const float* x0    = (const float*)d_in[0];
  const float* x1    = (const float*)d_in[1];
  const float* wq    = (const float*)d_in[2];
  const float* bq    = (const float*)d_in[3];
  const float* wk    = (const float*)d_in[4];
  const float* bk    = (const float*)d_in[5];
  const float* gamma = (const float*)d_in[6];

  unsigned short* qf  = (unsigned short*)d_ws;                   // 1 MB (fragment layout)
  unsigned short* kT  = qf + (size_t)B_ * W_ * DQK_;             // 1 MB
  unsigned short* x0f = kT + (size_t)B_ * W_ * DQK_;             // 8 MB fragment tiles

  float* out = (float*)d_out;                                    // [B][C][W]
  float* att = out + (size_t)B_ * C_ * W_;                       // [B][W][W]

  sa_prep <<<dim3(64, 4), 512, 0, stream>>>(x0, x1, wq, bq, wk, bk, qf, kT, x0f);
  sa_fused<<<1024, 256, 0, stream>>>(qf, kT, x0f, x1, gamma, out, att);
}

// Round 20
// 143.226 us; speedup vs baseline: 1.1275x; 1.1275x over previous
//
#include <hip/hip_runtime.h>
#include <stdint.h>

#define B_    4
#define C_    256
#define W_    4096
#define DQK_  32
#define NT64_ 64      // 64-wide n tiles per batch
#define TSZ_  16384   // shorts per x0f tile (32 frags x 64 lane x 8)

typedef short bf16x8 __attribute__((ext_vector_type(8)));
typedef float f32x4  __attribute__((ext_vector_type(4)));

__device__ __forceinline__ float fexp2f(float x){
#if __has_builtin(__builtin_amdgcn_exp2f)
  return __builtin_amdgcn_exp2f(x);
#else
  return exp2f(x);
#endif
}
__device__ __forceinline__ float frcpf(float x){
#if __has_builtin(__builtin_amdgcn_rcpf)
  return __builtin_amdgcn_rcpf(x);
#else
  return 1.0f / x;
#endif
}
// single-instruction packed f32->bf16 (RTNE)
__device__ __forceinline__ uint32_t cvtpk(float a, float b){
  uint32_t r;
  asm("v_cvt_pk_bf16_f32 %0, %1, %2" : "=v"(r) : "v"(a), "v"(b));
  return r;
}
__device__ __forceinline__ unsigned short bf16c(float f){
  return (unsigned short)cvtpk(f, f);
}

// ---------------------------------------------------------------------------
// K1: UNCHANGED from R15 (wave-uniform weight c-slices -> scalar broadcasts).
// ---------------------------------------------------------------------------
__global__ __launch_bounds__(512) void sa_prep(
    const float* __restrict__ x0, const float* __restrict__ x1,
    const float* __restrict__ wq, const float* __restrict__ bq,
    const float* __restrict__ wk, const float* __restrict__ bk,
    unsigned short* __restrict__ qf, unsigned short* __restrict__ kT,
    unsigned short* __restrict__ x0f)
{
  const int b    = blockIdx.y;
  const int nt   = blockIdx.x;                 // 64-n tile index
  const int tid  = threadIdx.x;
  const int lane = tid & 63;
  const int cq   = __builtin_amdgcn_readfirstlane(tid >> 6);   // 0..7, uniform
  const int n    = nt * 64 + lane;
  const int lr   = lane & 15, lg = lane >> 4;
  const size_t bw = (size_t)b * ((size_t)C_ * W_) + n;

  __shared__ union {
    unsigned short xs[256 * 68];   // bf16 stage [c][n-local], pitch 68
    float red[8][64][33];          // cross-wave reduce
  } sm;

  float accq[DQK_], acck[DQK_];
  #pragma unroll
  for (int d = 0; d < DQK_; ++d){ accq[d] = 0.f; acck[d] = 0.f; }

  const int c0 = cq * 32;
  for (int i = 0; i < 32; ++i){
    const int c = c0 + i;                      // wave-uniform
    const size_t off = bw + (size_t)c * W_;
    const float v0 = x0[off];
    const float v1 = x1[off];
    sm.xs[c * 68 + lane] = bf16c(v0);
    #pragma unroll
    for (int d = 0; d < DQK_; ++d){
      accq[d] = fmaf(wq[d * C_ + c], v0, accq[d]);   // scalar loads (uniform)
      acck[d] = fmaf(wk[d * C_ + c], v1, acck[d]);
    }
  }

  // ---- flush x0f (intra-wave dependency only) ----
  {
    unsigned short* xt = x0f + (size_t)(b * NT64_ + nt) * TSZ_;
    #pragma unroll
    for (int ct = 0; ct < 2; ++ct)
      #pragma unroll
      for (int ks = 0; ks < 2; ++ks){
        uint4 v = *(const uint4*)&sm.xs[(c0 + ct * 16 + lr) * 68 + ks * 32 + lg * 8];
        *(uint4*)(xt + ((size_t)((cq * 2 + ct) * 2 + ks) * 64 + lane) * 8) = v;
      }
  }
  __syncthreads();   // xs reads done -> red may overwrite

  // ---- q reduce + fragment-layout pack ----
  #pragma unroll
  for (int d = 0; d < DQK_; ++d) sm.red[cq][lane][d] = accq[d];
  __syncthreads();
  {
    const int nl = tid & 63, dg = tid >> 6;
    const int d0 = dg * 4;
    float s[4];
    #pragma unroll
    for (int j = 0; j < 4; ++j){
      float t = bq[d0 + j];
      #pragma unroll
      for (int g = 0; g < 8; ++g) t += sm.red[g][nl][d0 + j];
      s[j] = t;
    }
    uint2 pk; pk.x = cvtpk(s[0], s[1]); pk.y = cvtpk(s[2], s[3]);
    const int ng = nt * 64 + nl;
    const size_t addr = (((size_t)b * 256 + (ng >> 4)) * 64
                         + (ng & 15) + ((dg >> 1) << 4)) * 8 + (dg & 1) * 4;
    *(uint2*)(qf + addr) = pk;
  }
  __syncthreads();

  // ---- k reduce + row-major pack (scaled) ----
  #pragma unroll
  for (int d = 0; d < DQK_; ++d) sm.red[cq][lane][d] = acck[d];
  __syncthreads();
  {
    const float SCL = 0.0625f * 1.44269504088896340736f; // 1/sqrt(256)*log2(e)
    const int nl = tid & 63, dg = tid >> 6;
    const int d0 = dg * 4;
    float s[4];
    #pragma unroll
    for (int j = 0; j < 4; ++j){
      float t = bk[d0 + j];
      #pragma unroll
      for (int g = 0; g < 8; ++g) t += sm.red[g][nl][d0 + j];
      s[j] = t * SCL;
    }
    uint2 pk; pk.x = cvtpk(s[0], s[1]); pk.y = cvtpk(s[2], s[3]);
    *(uint2*)(kT + ((size_t)b * W_ + nt * 64 + nl) * DQK_ + d0) = pk;
  }
}

// ---------------------------------------------------------------------------
// K2 (R20): BARRIER-FREE, m32, minimal traffic. Block 512 thr = 8 waves =
// (ch 0..1 c-half) x (nq 0..3 n-quarter). Wave: acc c128 x m32 partial over
// its 1024-n quarter (16 epochs x 64-n, two K32 halves each). Per half:
// 2 energy MFMA x 2 m-tiles (q prefetched a half ahead), exp2*invS, att f32x4
// stores (ch==0 only), in-register P transpose (8 ds_bpermute per pf, R19's
// verified mapping), 16 PV MFMA vs af regs (double-buffered per half; reload
// issued right after use -> full-half latency window). NO barriers / LDS
// tiles / vmcnt drains in the loop. Epilogue: 4 LDS reduce rounds over nq.
// x0f traffic: 2MB/block (ch,nq disjoint) -> 256MB/batch ~30us pair-L2.
// grid 512 (XCD-paired), ~210 VGPR -> 1 block/CU, 2 grid rounds.
// ---------------------------------------------------------------------------
__global__ __launch_bounds__(512, 2) void sa_fused(
    const unsigned short* __restrict__ qf, const unsigned short* __restrict__ kT,
    const unsigned short* __restrict__ x0f, const float* __restrict__ x1,
    const float* __restrict__ gamma,
    float* __restrict__ out, float* __restrict__ att)
{
  const int lb = blockIdx.x;
  const int b    = (lb & 7) >> 1;                    // batch -> XCD pair
  const int mblk = ((lb >> 3) << 1) | (lb & 1);      // 0..127
  const int m0 = mblk * 32;
  const int tid = threadIdx.x;
  const int lane = tid & 63;
  const int wid = tid >> 6;                          // 0..7
  const int nq = wid & 3;                            // n-quarter
  const int ch = wid >> 2;                           // c-half
  const int lr = lane & 15, lg = lane >> 4;

  __shared__ float ssum[8][32];
  __shared__ __align__(16) float red[4][8][64][4];   // 32KB epilogue reduce

  const f32x4 z4 = {0.f, 0.f, 0.f, 0.f};
  const bf16x8 kf0 = *(const bf16x8*)(kT + ((size_t)b * W_ + m0 + lr) * DQK_ + lg * 8);
  const bf16x8 kf1 = *(const bf16x8*)(kT + ((size_t)b * W_ + m0 + 16 + lr) * DQK_ + lg * 8);

  // q: tile t (16-n) at qbase + t*512; wave's quarter starts at tile 64*nq
  const unsigned short* qbase = qf + (size_t)b * 256 * 512 + (size_t)lane * 8;
  // x0f: epoch tile nt at xbase + nt*TSZ_; frag (ct,ks) at +(ch*16+ct*2+ks)*512
  const unsigned short* xbase = x0f + (size_t)b * NT64_ * TSZ_
                                + (size_t)(ch * 16) * 512 + (size_t)lane * 8;

  // ---- pass 1: denominators over wave's n-quarter (barrier-free) ----
  float ps0 = 0.f, ps1 = 0.f;
  {
    const unsigned short* qq = qbase + (size_t)(nq * 64) * 512;
    bf16x8 qv = *(const bf16x8*)qq;
    for (int i = 0; i < 64; ++i){
      bf16x8 qn = *(const bf16x8*)(qq + 512);   // last read spills into kT: harmless
      qq += 512;
      f32x4 e0 = __builtin_amdgcn_mfma_f32_16x16x32_bf16(qv, kf0, z4, 0, 0, 0);
      f32x4 e1 = __builtin_amdgcn_mfma_f32_16x16x32_bf16(qv, kf1, z4, 0, 0, 0);
      ps0 += (fexp2f(e0[0]) + fexp2f(e0[1])) + (fexp2f(e0[2]) + fexp2f(e0[3]));
      ps1 += (fexp2f(e1[0]) + fexp2f(e1[1])) + (fexp2f(e1[2]) + fexp2f(e1[3]));
      qv = qn;
    }
  }
  ps0 += __shfl_xor(ps0, 16); ps0 += __shfl_xor(ps0, 32);
  ps1 += __shfl_xor(ps1, 16); ps1 += __shfl_xor(ps1, 32);
  if (lane < 16){
    ssum[wid][lane]      = ps0;
    ssum[wid][16 + lane] = ps1;
  }
  __syncthreads();
  const float is0 = frcpf(ssum[0][lr] + ssum[1][lr] + ssum[2][lr] + ssum[3][lr]);
  const float is1 = frcpf(ssum[0][16 + lr] + ssum[1][16 + lr] + ssum[2][16 + lr] + ssum[3][16 + lr]);

  // ---- pass 2: barrier-free main loop ----
  f32x4 acc[8][2];
  #pragma unroll
  for (int ct = 0; ct < 8; ++ct){ acc[ct][0] = z4; acc[ct][1] = z4; }

  const unsigned short* afp = xbase + (size_t)(nq * 16) * TSZ_;
  bf16x8 afE[8], afO[8];
  #pragma unroll
  for (int ct = 0; ct < 8; ++ct) afE[ct] = *(const bf16x8*)(afp + (ct * 2 + 0) * 512);
  #pragma unroll
  for (int ct = 0; ct < 8; ++ct) afO[ct] = *(const bf16x8*)(afp + (ct * 2 + 1) * 512);

  const unsigned short* qp = qbase + (size_t)(nq * 64) * 512;
  bf16x8 qA0 = *(const bf16x8*)(qp);
  bf16x8 qA1 = *(const bf16x8*)(qp + 512);
  bf16x8 qB0 = *(const bf16x8*)(qp + 1024);
  bf16x8 qB1 = *(const bf16x8*)(qp + 1536);

  float* attw0 = att + ((size_t)b * W_ + m0 + lr) * W_ + nq * 1024 + lg * 4;
  float* attw1 = attw0 + (size_t)16 * W_;

  const int sA = (lr + 32 * (lg & 1)) * 4;
  const int sB = sA + 64;
  const bool hi = (lg & 2) != 0;

  #define TRANSPOSE_PF(PJ0, PJ1, PF)                                             \
  {                                                                              \
    const uint32_t c0 = cvtpk((PJ0)[0], (PJ0)[1]), c1 = cvtpk((PJ0)[2], (PJ0)[3]);\
    const uint32_t c2 = cvtpk((PJ1)[0], (PJ1)[1]), c3 = cvtpk((PJ1)[2], (PJ1)[3]);\
    const uint32_t a0 = (uint32_t)__builtin_amdgcn_ds_bpermute(sA, (int)c0);     \
    const uint32_t a1 = (uint32_t)__builtin_amdgcn_ds_bpermute(sA, (int)c1);     \
    const uint32_t a2 = (uint32_t)__builtin_amdgcn_ds_bpermute(sB, (int)c0);     \
    const uint32_t a3 = (uint32_t)__builtin_amdgcn_ds_bpermute(sB, (int)c1);     \
    const uint32_t b0 = (uint32_t)__builtin_amdgcn_ds_bpermute(sA, (int)c2);     \
    const uint32_t b1 = (uint32_t)__builtin_amdgcn_ds_bpermute(sA, (int)c3);     \
    const uint32_t b2 = (uint32_t)__builtin_amdgcn_ds_bpermute(sB, (int)c2);     \
    const uint32_t b3 = (uint32_t)__builtin_amdgcn_ds_bpermute(sB, (int)c3);     \
    union { uint32_t u[4]; bf16x8 v; } pfu_;                                     \
    pfu_.u[0] = hi ? b0 : a0;                                                    \
    pfu_.u[1] = hi ? b1 : a1;                                                    \
    pfu_.u[2] = hi ? b2 : a2;                                                    \
    pfu_.u[3] = hi ? b3 : a3;                                                    \
    PF = pfu_.v;                                                                 \
  }

  for (int e = 0; e < 16; ++e){
    const bool more = (e != 15);
    // ======== half ks=0: energy uses qA, PV uses afE ========
    {
      f32x4 e00 = __builtin_amdgcn_mfma_f32_16x16x32_bf16(qA0, kf0, z4, 0, 0, 0);
      f32x4 e01 = __builtin_amdgcn_mfma_f32_16x16x32_bf16(qA0, kf1, z4, 0, 0, 0);
      f32x4 e10 = __builtin_amdgcn_mfma_f32_16x16x32_bf16(qA1, kf0, z4, 0, 0, 0);
      f32x4 e11 = __builtin_amdgcn_mfma_f32_16x16x32_bf16(qA1, kf1, z4, 0, 0, 0);
      if (more){                              // reload qA for (e+1, ks0) now
        qA0 = *(const bf16x8*)(qp + 2048);
        qA1 = *(const bf16x8*)(qp + 2048 + 512);
      }
      f32x4 p00, p01, p10, p11;
      #pragma unroll
      for (int r = 0; r < 4; ++r){
        p00[r] = fexp2f(e00[r]) * is0;   // j=0, mt=0
        p01[r] = fexp2f(e01[r]) * is1;   // j=0, mt=1
        p10[r] = fexp2f(e10[r]) * is0;   // j=1, mt=0
        p11[r] = fexp2f(e11[r]) * is1;   // j=1, mt=1
      }
      if (ch == 0){
        *(f32x4*)(attw0)      = p00;
        *(f32x4*)(attw0 + 16) = p10;
        *(f32x4*)(attw1)      = p01;
        *(f32x4*)(attw1 + 16) = p11;
      }
      bf16x8 pf0, pf1;
      TRANSPOSE_PF(p00, p10, pf0);
      TRANSPOSE_PF(p01, p11, pf1);
      #pragma unroll
      for (int ct = 0; ct < 8; ++ct){
        acc[ct][0] = __builtin_amdgcn_mfma_f32_16x16x32_bf16(afE[ct], pf0, acc[ct][0], 0, 0, 0);
        acc[ct][1] = __builtin_amdgcn_mfma_f32_16x16x32_bf16(afE[ct], pf1, acc[ct][1], 0, 0, 0);
      }
      if (more){                              // reload afE for (e+1, ks0)
        #pragma unroll
        for (int ct = 0; ct < 8; ++ct)
          afE[ct] = *(const bf16x8*)(afp + TSZ_ + (ct * 2 + 0) * 512);
      }
    }
    // ======== half ks=1: energy uses qB, PV uses afO ========
    {
      f32x4 e00 = __builtin_amdgcn_mfma_f32_16x16x32_bf16(qB0, kf0, z4, 0, 0, 0);
      f32x4 e01 = __builtin_amdgcn_mfma_f32_16x16x32_bf16(qB0, kf1, z4, 0, 0, 0);
      f32x4 e10 = __builtin_amdgcn_mfma_f32_16x16x32_bf16(qB1, kf0, z4, 0, 0, 0);
      f32x4 e11 = __builtin_amdgcn_mfma_f32_16x16x32_bf16(qB1, kf1, z4, 0, 0, 0);
      if (more){                              // reload qB for (e+1, ks1)
        qB0 = *(const bf16x8*)(qp + 2048 + 1024);
        qB1 = *(const bf16x8*)(qp + 2048 + 1536);
      }
      f32x4 p00, p01, p10, p11;
      #pragma unroll
      for (int r = 0; r < 4; ++r){
        p00[r] = fexp2f(e00[r]) * is0;
        p01[r] = fexp2f(e01[r]) * is1;
        p10[r] = fexp2f(e10[r]) * is0;
        p11[r] = fexp2f(e11[r]) * is1;
      }
      if (ch == 0){
        *(f32x4*)(attw0 + 32) = p00;
        *(f32x4*)(attw0 + 48) = p10;
        *(f32x4*)(attw1 + 32) = p01;
        *(f32x4*)(attw1 + 48) = p11;
      }
      bf16x8 pf0, pf1;
      TRANSPOSE_PF(p00, p10, pf0);
      TRANSPOSE_PF(p01, p11, pf1);
      #pragma unroll
      for (int ct = 0; ct < 8; ++ct){
        acc[ct][0] = __builtin_amdgcn_mfma_f32_16x16x32_bf16(afO[ct], pf0, acc[ct][0], 0, 0, 0);
        acc[ct][1] = __builtin_amdgcn_mfma_f32_16x16x32_bf16(afO[ct], pf1, acc[ct][1], 0, 0, 0);
      }
      if (more){                              // reload afO for (e+1, ks1)
        #pragma unroll
        for (int ct = 0; ct < 8; ++ct)
          afO[ct] = *(const bf16x8*)(afp + TSZ_ + (ct * 2 + 1) * 512);
      }
    }
    qp += 2048;        // 4 q-tiles per epoch
    afp += TSZ_;       // next 64-n x0f tile
    attw0 += 64; attw1 += 64;
  }
  #undef TRANSPOSE_PF

  // ---- epilogue: reduce acc over nq (4-way), out = gamma*s + x1 ----
  const float g = gamma[0];
  const float* x1b = x1 + (size_t)b * C_ * W_;
  float* outb = out + (size_t)b * C_ * W_;
  #pragma unroll
  for (int mt = 0; mt < 2; ++mt){
    #pragma unroll
    for (int chR = 0; chR < 2; ++chR){
      __syncthreads();
      if (ch == chR){
        #pragma unroll
        for (int ct = 0; ct < 8; ++ct)
          *(f32x4*)&red[nq][ct][lane][0] = acc[ct][mt];
      }
      __syncthreads();
      // all 8 waves: wave wid reduces c-tile ct = wid of chR's half
      f32x4 s = *(const f32x4*)&red[0][wid][lane][0];
      #pragma unroll
      for (int w = 1; w < 4; ++w) s += *(const f32x4*)&red[w][wid][lane][0];
      #pragma unroll
      for (int r = 0; r < 4; ++r){
        const int c = (chR * 8 + wid) * 16 + lg * 4 + r;
        const size_t idx = (size_t)c * W_ + m0 + mt * 16 + lr;
        outb[idx] = fmaf(g, s[r], x1b[idx]);
      }
    }
  }
}

extern "C" void kernel_launch(void* const* d_in, const int* in_sizes, int n_in,
                              void* d_out, int out_size, void* d_ws, size_t ws_size,
                              hipStream_t stream)
{
  (void)in_sizes; (void)n_in; (void)out_size; (void)ws_size;
  const float* x0    = (const float*)d_in[0];
  const float* x1    = (const float*)d_in[1];
  const float* wq    = (const float*)d_in[2];
  const float* bq    = (const float*)d_in[3];
  const float* wk    = (const float*)d_in[4];
  const float* bk    = (const float*)d_in[5];
  const float* gamma = (const float*)d_in[6];

  unsigned short* qf  = (unsigned short*)d_ws;                   // 1 MB (fragment layout)
  unsigned short* kT  = qf + (size_t)B_ * W_ * DQK_;             // 1 MB
  unsigned short* x0f = kT + (size_t)B_ * W_ * DQK_;             // 8 MB fragment tiles

  float* out = (float*)d_out;                                    // [B][C][W]
  float* att = out + (size_t)B_ * C_ * W_;                       // [B][W][W]

  sa_prep <<<dim3(64, 4), 512, 0, stream>>>(x0, x1, wq, bq, wk, bk, qf, kT, x0f);
  sa_fused<<<512, 512, 0, stream>>>(qf, kT, x0f, x1, gamma, out, att);
}

// Round 21
// 125.762 us; speedup vs baseline: 1.2841x; 1.1389x over previous
//
#include <hip/hip_runtime.h>
#include <stdint.h>

#define B_    4
#define C_    256
#define W_    4096
#define DQK_  32
#define NT64_ 64      // 64-wide n tiles per batch
#define TSZ_  16384   // shorts per x0f tile (8 wb x 4 frag x 64 lane x 8)

typedef short bf16x8 __attribute__((ext_vector_type(8)));
typedef float f32x4  __attribute__((ext_vector_type(4)));

__device__ __forceinline__ float fexp2f(float x){
#if __has_builtin(__builtin_amdgcn_exp2f)
  return __builtin_amdgcn_exp2f(x);
#else
  return exp2f(x);
#endif
}
__device__ __forceinline__ float frcpf(float x){
#if __has_builtin(__builtin_amdgcn_rcpf)
  return __builtin_amdgcn_rcpf(x);
#else
  return 1.0f / x;
#endif
}
// single-instruction packed f32->bf16 (RTNE)
__device__ __forceinline__ uint32_t cvtpk(float a, float b){
  uint32_t r;
  asm("v_cvt_pk_bf16_f32 %0, %1, %2" : "=v"(r) : "v"(a), "v"(b));
  return r;
}
__device__ __forceinline__ unsigned short bf16c(float f){
  return (unsigned short)cvtpk(f, f);
}

// ---------------------------------------------------------------------------
// K1: R15 prep (wave-uniform weight c-slices -> scalar broadcasts; coalesced
// x0/x1 reads with lane=n; x0f flushed in PV-fragment layout via LDS stage).
// ---------------------------------------------------------------------------
__global__ __launch_bounds__(512) void sa_prep(
    const float* __restrict__ x0, const float* __restrict__ x1,
    const float* __restrict__ wq, const float* __restrict__ bq,
    const float* __restrict__ wk, const float* __restrict__ bk,
    unsigned short* __restrict__ qf, unsigned short* __restrict__ kT,
    unsigned short* __restrict__ x0f)
{
  const int b    = blockIdx.y;
  const int nt   = blockIdx.x;                 // 64-n tile index
  const int tid  = threadIdx.x;
  const int lane = tid & 63;
  const int cq   = __builtin_amdgcn_readfirstlane(tid >> 6);   // 0..7, uniform
  const int n    = nt * 64 + lane;
  const int lr   = lane & 15, lg = lane >> 4;
  const size_t bw = (size_t)b * ((size_t)C_ * W_) + n;

  __shared__ union {
    unsigned short xs[256 * 68];   // bf16 stage [c][n-local], pitch 68
    float red[8][64][33];          // cross-wave reduce
  } sm;

  float accq[DQK_], acck[DQK_];
  #pragma unroll
  for (int d = 0; d < DQK_; ++d){ accq[d] = 0.f; acck[d] = 0.f; }

  const int c0 = cq * 32;
  for (int i = 0; i < 32; ++i){
    const int c = c0 + i;                      // wave-uniform
    const size_t off = bw + (size_t)c * W_;
    const float v0 = x0[off];
    const float v1 = x1[off];
    sm.xs[c * 68 + lane] = bf16c(v0);
    #pragma unroll
    for (int d = 0; d < DQK_; ++d){
      accq[d] = fmaf(wq[d * C_ + c], v0, accq[d]);   // scalar loads (uniform)
      acck[d] = fmaf(wk[d * C_ + c], v1, acck[d]);
    }
  }

  // ---- flush x0f (intra-wave dependency only) ----
  {
    unsigned short* xt = x0f + (size_t)(b * NT64_ + nt) * TSZ_;
    #pragma unroll
    for (int ct = 0; ct < 2; ++ct)
      #pragma unroll
      for (int ks = 0; ks < 2; ++ks){
        uint4 v = *(const uint4*)&sm.xs[(c0 + ct * 16 + lr) * 68 + ks * 32 + lg * 8];
        *(uint4*)(xt + ((size_t)((cq * 2 + ct) * 2 + ks) * 64 + lane) * 8) = v;
      }
  }
  __syncthreads();   // xs reads done -> red may overwrite

  // ---- q reduce + fragment-layout pack ----
  #pragma unroll
  for (int d = 0; d < DQK_; ++d) sm.red[cq][lane][d] = accq[d];
  __syncthreads();
  {
    const int nl = tid & 63, dg = tid >> 6;
    const int d0 = dg * 4;
    float s[4];
    #pragma unroll
    for (int j = 0; j < 4; ++j){
      float t = bq[d0 + j];
      #pragma unroll
      for (int g = 0; g < 8; ++g) t += sm.red[g][nl][d0 + j];
      s[j] = t;
    }
    uint2 pk; pk.x = cvtpk(s[0], s[1]); pk.y = cvtpk(s[2], s[3]);
    const int ng = nt * 64 + nl;
    const size_t addr = (((size_t)b * 256 + (ng >> 4)) * 64
                         + (ng & 15) + ((dg >> 1) << 4)) * 8 + (dg & 1) * 4;
    *(uint2*)(qf + addr) = pk;
  }
  __syncthreads();

  // ---- k reduce + row-major pack (scaled) ----
  #pragma unroll
  for (int d = 0; d < DQK_; ++d) sm.red[cq][lane][d] = acck[d];
  __syncthreads();
  {
    const float SCL = 0.0625f * 1.44269504088896340736f; // 1/sqrt(256)*log2(e)
    const int nl = tid & 63, dg = tid >> 6;
    const int d0 = dg * 4;
    float s[4];
    #pragma unroll
    for (int j = 0; j < 4; ++j){
      float t = bk[d0 + j];
      #pragma unroll
      for (int g = 0; g < 8; ++g) t += sm.red[g][nl][d0 + j];
      s[j] = t * SCL;
    }
    uint2 pk; pk.x = cvtpk(s[0], s[1]); pk.y = cvtpk(s[2], s[3]);
    *(uint2*)(kT + ((size_t)b * W_ + nt * 64 + nl) * DQK_ + d0) = pk;
  }
}

// ---------------------------------------------------------------------------
// K2 (R16 = best measured, 126.9us): m-tile 64 per block, 256 blocks (1/CU),
// 8 waves = (nq 0..3, mh 0..1). Per iter: 2 energy MFMA (shared qv) -> P
// (2x8KB swizzled LDS dbuf) -> pure-lgkmcnt barrier -> NT att stores + reg
// prefetch of next q/af -> 16 PV MFMA vs register x0f fragments.
// ---------------------------------------------------------------------------
__global__ __launch_bounds__(512, 2) void sa_fused(
    const unsigned short* __restrict__ qf, const unsigned short* __restrict__ kT,
    const unsigned short* __restrict__ x0f, const float* __restrict__ x1,
    const float* __restrict__ gamma,
    float* __restrict__ out, float* __restrict__ att)
{
  const int lb = blockIdx.x;
  const int b    = (lb & 7) >> 1;                    // batch -> XCD pair
  const int mblk = ((lb >> 3) << 1) | (lb & 1);      // 0..63
  const int m0 = mblk * 64;
  const int tid = threadIdx.x;
  const int lane = tid & 63;
  const int wid = tid >> 6;                          // 0..7
  const int lr = lane & 15, lg = lane >> 4;
  const int nq = wid >> 1;                           // n-quarter 0..3
  const int mh = wid & 1;                            // m-half 0..1

  __shared__ __align__(16) unsigned short Plds[2][64 * 64]; // 2 x 8KB, swizzled
  __shared__ float ssum[4][64];

  const int row0 = mh * 32 + lr, row1 = row0 + 16;
  const bf16x8 kf0 = *(const bf16x8*)(kT + ((size_t)b * W_ + m0 + row0) * DQK_ + lg * 8);
  const bf16x8 kf1 = *(const bf16x8*)(kT + ((size_t)b * W_ + m0 + row1) * DQK_ + lg * 8);
  const unsigned short* qfw = qf + ((size_t)b * 256 * 64 + (size_t)nq * 64 + lane) * 8;
  const unsigned short* afw = x0f + (size_t)b * NT64_ * TSZ_ + wid * 2048 + lane * 8;

  // ---- pass 1: denominators (energy-only), q prefetched 1 iter ahead ----
  float ps0 = 0.f, ps1 = 0.f;
  {
    const unsigned short* qp = qfw + 2048;
    bf16x8 qv = *(const bf16x8*)qfw;
    for (int s = 0; s < NT64_; ++s){
      bf16x8 qn = *(const bf16x8*)qp;
      qp = (s == NT64_ - 2) ? qfw : (qp + 2048);
      f32x4 e0 = __builtin_amdgcn_mfma_f32_16x16x32_bf16(qv, kf0, (f32x4){0.f,0.f,0.f,0.f}, 0, 0, 0);
      f32x4 e1 = __builtin_amdgcn_mfma_f32_16x16x32_bf16(qv, kf1, (f32x4){0.f,0.f,0.f,0.f}, 0, 0, 0);
      ps0 += (fexp2f(e0[0]) + fexp2f(e0[1])) + (fexp2f(e0[2]) + fexp2f(e0[3]));
      ps1 += (fexp2f(e1[0]) + fexp2f(e1[1])) + (fexp2f(e1[2]) + fexp2f(e1[3]));
      qv = qn;
    }
  }
  ps0 += __shfl_xor(ps0, 16); ps0 += __shfl_xor(ps0, 32);
  ps1 += __shfl_xor(ps1, 16); ps1 += __shfl_xor(ps1, 32);
  if (lane < 16){
    ssum[nq][mh * 32 + lane]      = ps0;
    ssum[nq][mh * 32 + 16 + lane] = ps1;
  }
  __syncthreads();
  const float is0 = frcpf(ssum[0][row0] + ssum[1][row0] + ssum[2][row0] + ssum[3][row0]);
  const float is1 = frcpf(ssum[0][row1] + ssum[1][row1] + ssum[2][row1] + ssum[3][row1]);

  // ---- pass 2 ----
  f32x4 acc[2][4];
  #pragma unroll
  for (int ct = 0; ct < 2; ++ct)
    #pragma unroll
    for (int m2 = 0; m2 < 4; ++m2) acc[ct][m2] = (f32x4){0.f,0.f,0.f,0.f};

  const int pw0 = row0 * 64 + (((nq * 2 + (lg >> 1)) ^ (row0 & 7)) << 3) + (lg & 1) * 4;
  const int pw1 = row1 * 64 + (((nq * 2 + (lg >> 1)) ^ (row1 & 7)) << 3) + (lg & 1) * 4;
  int pfo[4][2];
  #pragma unroll
  for (int m2 = 0; m2 < 4; ++m2){
    const int prow = m2 * 16 + lr;
    #pragma unroll
    for (int ks = 0; ks < 2; ++ks)
      pfo[m2][ks] = prow * 64 + (((ks * 4 + lg) ^ (prow & 7)) << 3);
  }

  const unsigned short* qp = qfw + 2048;     // q tile for s+1
  const unsigned short* afp = afw + TSZ_;    // x0f tile for s+1
  float* attw0 = att + ((size_t)b * W_ + m0 + row0) * W_ + nq * 16 + lg * 4;
  float* attw1 = attw0 + (size_t)16 * W_;

  bf16x8 qv = *(const bf16x8*)qfw;           // q for s=0
  bf16x8 af0 = *(const bf16x8*)(afw);        // A-frags for s=0 (ct*2+ks order)
  bf16x8 af1 = *(const bf16x8*)(afw + 512);
  bf16x8 af2 = *(const bf16x8*)(afw + 1024);
  bf16x8 af3 = *(const bf16x8*)(afw + 1536);

  for (int s = 0; s < NT64_; ++s){
    const int cur = s & 1;

    // energy (2 quarters, shared qv) -> P[cur]
    f32x4 e0 = __builtin_amdgcn_mfma_f32_16x16x32_bf16(qv, kf0, (f32x4){0.f,0.f,0.f,0.f}, 0, 0, 0);
    f32x4 e1 = __builtin_amdgcn_mfma_f32_16x16x32_bf16(qv, kf1, (f32x4){0.f,0.f,0.f,0.f}, 0, 0, 0);
    f32x4 p0, p1;
    #pragma unroll
    for (int r = 0; r < 4; ++r){
      p0[r] = fexp2f(e0[r]) * is0;
      p1[r] = fexp2f(e1[r]) * is1;
    }
    uint2 pv0; pv0.x = cvtpk(p0[0], p0[1]); pv0.y = cvtpk(p0[2], p0[3]);
    uint2 pv1; pv1.x = cvtpk(p1[0], p1[1]); pv1.y = cvtpk(p1[2], p1[3]);
    *(uint2*)(&Plds[cur][0] + pw0) = pv0;
    *(uint2*)(&Plds[cur][0] + pw1) = pv1;

    // pure-LDS barrier: P[cur] visible; NO vmcnt drain
    asm volatile("s_waitcnt lgkmcnt(0)" ::: "memory");
    __builtin_amdgcn_sched_barrier(0);
    __builtin_amdgcn_s_barrier();

    // prefetch next-tile operands + store att(s)
    qv = *(const bf16x8*)qp;
    qp = (s == NT64_ - 2) ? qfw : (qp + 2048);
    bf16x8 an0 = *(const bf16x8*)(afp);
    bf16x8 an1 = *(const bf16x8*)(afp + 512);
    bf16x8 an2 = *(const bf16x8*)(afp + 1024);
    bf16x8 an3 = *(const bf16x8*)(afp + 1536);
    afp = (s == NT64_ - 2) ? afw : (afp + TSZ_);
    __builtin_nontemporal_store(p0, (f32x4*)attw0);
    __builtin_nontemporal_store(p1, (f32x4*)attw1);
    attw0 += 64; attw1 += 64;

    // PV: A = x0 fragments (registers), B = P[cur] (swizzled LDS)
    const unsigned short* Pb = &Plds[cur][0];
    bf16x8 pf[4][2];
    __builtin_amdgcn_s_setprio(1);
    #pragma unroll
    for (int m2 = 0; m2 < 4; ++m2)
      #pragma unroll
      for (int ks = 0; ks < 2; ++ks)
        pf[m2][ks] = *(const bf16x8*)(Pb + pfo[m2][ks]);
    #pragma unroll
    for (int m2 = 0; m2 < 4; ++m2){
      acc[0][m2] = __builtin_amdgcn_mfma_f32_16x16x32_bf16(af0, pf[m2][0], acc[0][m2], 0, 0, 0);
      acc[0][m2] = __builtin_amdgcn_mfma_f32_16x16x32_bf16(af1, pf[m2][1], acc[0][m2], 0, 0, 0);
      acc[1][m2] = __builtin_amdgcn_mfma_f32_16x16x32_bf16(af2, pf[m2][0], acc[1][m2], 0, 0, 0);
      acc[1][m2] = __builtin_amdgcn_mfma_f32_16x16x32_bf16(af3, pf[m2][1], acc[1][m2], 0, 0, 0);
    }
    __builtin_amdgcn_s_setprio(0);

    af0 = an0; af1 = an1; af2 = an2; af3 = an3;
  }

  // ---- epilogue: out[c][m] = gamma*acc + x1 (nontemporal both ways) ----
  const float g = gamma[0];
  const float* x1b = x1 + (size_t)b * C_ * W_;
  float* outb = out + (size_t)b * C_ * W_;
  #pragma unroll
  for (int ct = 0; ct < 2; ++ct)
    #pragma unroll
    for (int m2 = 0; m2 < 4; ++m2)
      #pragma unroll
      for (int r = 0; r < 4; ++r){
        const int c = wid * 32 + ct * 16 + lg * 4 + r;
        const size_t idx = (size_t)c * W_ + m0 + m2 * 16 + lr;
        const float xv = __builtin_nontemporal_load(&x1b[idx]);
        __builtin_nontemporal_store(fmaf(g, acc[ct][m2][r], xv), &outb[idx]);
      }
}

extern "C" void kernel_launch(void* const* d_in, const int* in_sizes, int n_in,
                              void* d_out, int out_size, void* d_ws, size_t ws_size,
                              hipStream_t stream)
{
  (void)in_sizes; (void)n_in; (void)out_size; (void)ws_size;
  const float* x0    = (const float*)d_in[0];
  const float* x1    = (const float*)d_in[1];
  const float* wq    = (const float*)d_in[2];
  const float* bq    = (const float*)d_in[3];
  const float* wk    = (const float*)d_in[4];
  const float* bk    = (const float*)d_in[5];
  const float* gamma = (const float*)d_in[6];

  unsigned short* qf  = (unsigned short*)d_ws;                   // 1 MB (fragment layout)
  unsigned short* kT  = qf + (size_t)B_ * W_ * DQK_;             // 1 MB
  unsigned short* x0f = kT + (size_t)B_ * W_ * DQK_;             // 8 MB fragment tiles

  float* out = (float*)d_out;                                    // [B][C][W]
  float* att = out + (size_t)B_ * C_ * W_;                       // [B][W][W]

  sa_prep <<<dim3(64, 4), 512, 0, stream>>>(x0, x1, wq, bq, wk, bk, qf, kT, x0f);
  sa_fused<<<256, 512, 0, stream>>>(qf, kT, x0f, x1, gamma, out, att);
}